// Round 8
// baseline (34436.884 us; speedup 1.0000x reference)
//
#include <hip/hip_runtime.h>

#define KNBR 32
#define NCELL 4096        // 16^3 Morton cells
#define MAXCHUNK 320      // ceil(20000/64)=313 <= 320
#define FCAP (MAXCHUNK * 64)
#define FT 320            // fps threads: 5 waves = exactly MAXCHUNK/64
#define NWAVE (FT / 64)

typedef unsigned long long u64;
typedef unsigned int u32;

// Reference-matching squared distance: ((dx*dx + dy*dy) + dz*dz), no FMA contraction.
__device__ __forceinline__ float sq_dist_nofma(float px, float py, float pz,
                                               float cx, float cy, float cz) {
    float dx = __fsub_rn(px, cx);
    float dy = __fsub_rn(py, cy);
    float dz = __fsub_rn(pz, cz);
    return __fadd_rn(__fadd_rn(__fmul_rn(dx, dx), __fmul_rn(dy, dy)), __fmul_rn(dz, dz));
}

__device__ __forceinline__ unsigned spread4(unsigned v) {
    return (v & 1u) | ((v & 2u) << 2) | ((v & 4u) << 4) | ((v & 8u) << 6);
}

// key = md_bits<<24 | (0x7FFF-orig)<<9 | chunk  (orig<32768, chunk<512).
// u64 max == (max md, then min orig); chunk id rides along for free.
// md >= 0 so float bits are monotone. Sentinels (orig=INT_MAX) -> key 0; real keys > 0.
__device__ __forceinline__ u64 pack_key(float md, int orig, int c) {
    return (orig != 0x7fffffff)
        ? (((u64)__float_as_uint(md) << 24) | ((u64)(0x7FFFu - (u32)orig) << 9) | (u64)c)
        : 0ull;
}

// K1: AoS -> SoA + norms + Morton cell id + within-cell rank (counting-sort pass 1)
__global__ void prep_kernel(const float* __restrict__ coord, int N,
                            float* __restrict__ sx, float* __restrict__ sy,
                            float* __restrict__ sz, float* __restrict__ sn,
                            int* __restrict__ cell, int* __restrict__ rank,
                            int* __restrict__ hist) {
    int i = blockIdx.x * blockDim.x + threadIdx.x;
    if (i < N) {
        float x = coord[3 * i + 0];
        float y = coord[3 * i + 1];
        float z = coord[3 * i + 2];
        sx[i] = x; sy[i] = y; sz[i] = z;
        sn[i] = __fadd_rn(__fadd_rn(__fmul_rn(x, x), __fmul_rn(y, y)), __fmul_rn(z, z));
        int ix = (int)(x * 16.0f); ix = ix < 0 ? 0 : (ix > 15 ? 15 : ix);
        int iy = (int)(y * 16.0f); iy = iy < 0 ? 0 : (iy > 15 ? 15 : iy);
        int iz = (int)(z * 16.0f); iz = iz < 0 ? 0 : (iz > 15 ? 15 : iz);
        unsigned mc = spread4(ix) | (spread4(iy) << 1) | (spread4(iz) << 2);
        cell[i] = (int)mc;
        rank[i] = atomicAdd(&hist[mc], 1);
    }
}

// K2: exclusive scan of 4096-bin histogram
__global__ __launch_bounds__(1024) void scan_kernel(const int* __restrict__ hist,
                                                    int* __restrict__ cellstart) {
    __shared__ int buf[1024];
    int t = threadIdx.x;
    int h0 = hist[4 * t], h1 = hist[4 * t + 1], h2 = hist[4 * t + 2], h3 = hist[4 * t + 3];
    int s = h0 + h1 + h2 + h3;
    buf[t] = s;
    __syncthreads();
    for (int off = 1; off < 1024; off <<= 1) {
        int v = (t >= off) ? buf[t - off] : 0;
        __syncthreads();
        buf[t] += v;
        __syncthreads();
    }
    int ex = buf[t] - s;
    cellstart[4 * t]     = ex;
    cellstart[4 * t + 1] = ex + h0;
    cellstart[4 * t + 2] = ex + h0 + h1;
    cellstart[4 * t + 3] = ex + h0 + h1 + h2;
}

// K3: scatter into Morton order, packed as (x, y, z, orig_idx_bits)
__global__ void scatter_kernel(const float* __restrict__ sx, const float* __restrict__ sy,
                               const float* __restrict__ sz,
                               const int* __restrict__ cell, const int* __restrict__ rank,
                               const int* __restrict__ cellstart, int N,
                               float4* __restrict__ pts) {
    int i = blockIdx.x * blockDim.x + threadIdx.x;
    if (i < N) {
        int pos = cellstart[cell[i]] + rank[i];
        pts[pos] = make_float4(sx[i], sy[i], sz[i], __int_as_float(i));
    }
}

// K3b: sentinel padding
__global__ void pad_kernel(float4* __restrict__ pts, int N, int cap) {
    int i = N + blockIdx.x * blockDim.x + threadIdx.x;
    if (i < cap) pts[i] = make_float4(1e18f, 1e18f, 1e18f, __int_as_float(0x7fffffff));
}

// K3c: per-chunk init — md vs original point 0, chunk sphere, chunk key, winner coords.
__global__ void init_chunk_kernel(const float4* __restrict__ pts,
                                  const float* __restrict__ coord,
                                  float* __restrict__ mdbuf,
                                  float4* __restrict__ spheres,
                                  u64* __restrict__ ckeys,
                                  float4* __restrict__ wxyz_g) {
    int c = blockIdx.x, lane = threadIdx.x;
    int pos = (c << 6) + lane;
    float4 P = pts[pos];
    int orig = __float_as_int(P.w);
    bool real = (orig != 0x7fffffff);
    float c0x = coord[0], c0y = coord[1], c0z = coord[2];
    float d = sq_dist_nofma(P.x, P.y, P.z, c0x, c0y, c0z);
    float m = real ? d : -3e38f;
    mdbuf[pos] = m;
    u64 kself = pack_key(m, orig, c);
    u64 key = kself;
    float mnx = real ? P.x : 1e30f, mxx = real ? P.x : -1e30f;
    float mny = real ? P.y : 1e30f, mxy = real ? P.y : -1e30f;
    float mnz = real ? P.z : 1e30f, mxz = real ? P.z : -1e30f;
    #pragma unroll
    for (int off = 32; off; off >>= 1) {
        u64 k2 = __shfl_xor(key, off, 64);
        if (k2 > key) key = k2;
        mnx = fminf(mnx, __shfl_xor(mnx, off, 64));
        mxx = fmaxf(mxx, __shfl_xor(mxx, off, 64));
        mny = fminf(mny, __shfl_xor(mny, off, 64));
        mxy = fmaxf(mxy, __shfl_xor(mxy, off, 64));
        mnz = fminf(mnz, __shfl_xor(mnz, off, 64));
        mxz = fmaxf(mxz, __shfl_xor(mxz, off, 64));
    }
    if (kself == key) wxyz_g[c] = make_float4(P.x, P.y, P.z, 0.f);  // unique owner lane
    if (lane == 0) {
        float cx = 0.5f * (mnx + mxx), cy = 0.5f * (mny + mxy), cz = 0.5f * (mnz + mxz);
        float ex = (mxx - mnx) * 0.5f, ey = (mxy - mny) * 0.5f, ez = (mxz - mnz) * 0.5f;
        float r = sqrtf(ex * ex + ey * ey + ez * ez) * 1.0001f + 1e-7f;
        spheres[c] = make_float4(cx, cy, cz, r);
        ckeys[c] = key;
    }
}

// K4: chunked FPS, round-8 skeleton. 2 barriers/step, zero atomics, zero global loads
// on the argmax critical path. Per-wave chunk ownership: wave w owns chunks
// [64w, 64w+64); prune -> ballot -> iterate own mask bits.
// Race-free winner coords: wave-max owner snapshots wxyz[tid] into wcoord[wv]
// BEFORE barrier 1; phase C (after barrier 1) only writes wxyz/keys, which are next
// read in phase A after barrier 2.
__global__ __launch_bounds__(FT)
void fps_kernel(const float4* __restrict__ pts, float* __restrict__ mdbuf,
                const float4* __restrict__ spheres_g, const u64* __restrict__ ckeys_g,
                const float4* __restrict__ wxyz_g,
                int nchunk, int n_dst, int* __restrict__ out_idx) {
    __shared__ u64    keys[MAXCHUNK];
    __shared__ float4 wxyz[MAXCHUNK];
    __shared__ u64    wwin[NWAVE];
    __shared__ float4 wcoord[NWAVE];

    const int tid = threadIdx.x, lane = tid & 63, wv = tid >> 6;

    for (int i = tid; i < MAXCHUNK; i += FT) {
        keys[i] = (i < nchunk) ? ckeys_g[i] : 0ull;
        wxyz[i] = (i < nchunk) ? wxyz_g[i] : make_float4(0.f, 0.f, 0.f, 0.f);
    }
    float4 S = make_float4(0.f, 0.f, 0.f, 0.f);
    if (tid < nchunk) S = spheres_g[tid];        // static tid<->chunk map: load once
    if (tid < NWAVE) wwin[tid] = 0ull;
    if (tid == 0) out_idx[0] = 0;
    __syncthreads();

    for (int s = 1; s < n_dst; ++s) {
        // A: argmax over chunk keys. k0 doubles as this thread's chunk maxmd for prune.
        u64 k0 = (tid < nchunk) ? keys[tid] : 0ull;
        u64 k = k0;
        #pragma unroll
        for (int off = 32; off; off >>= 1) {
            u64 k2 = __shfl_xor(k, off, 64);
            if (k2 > k) k = k2;
        }
        if (k0 == k && k0 != 0ull) {             // unique owner (keys embed chunk id)
            wwin[wv]   = k;
            wcoord[wv] = wxyz[tid];              // snapshot winner coords pre-barrier
        }
        __syncthreads();                         // barrier 1
        u64 kb = wwin[0]; int wb = 0;
        #pragma unroll
        for (int w = 1; w < NWAVE; ++w) { u64 t2 = wwin[w]; if (t2 > kb) { kb = t2; wb = w; } }
        float4 C4 = wcoord[wb];
        float ncx = C4.x, ncy = C4.y, ncz = C4.z;
        if (tid == 0) out_idx[s] = (int)(0x7FFFu - (u32)((kb >> 9) & 0x7FFFull));

        // B: conservative sphere prune (registers + ballot only).
        // Pruned chunk: for all p, d(p,nc) >= D - r > sqrt(maxmd) => no md change.
        // Winner's chunk never pruned (nc inside its own sphere).
        bool active = false;
        if (tid < nchunk) {
            float maxmd = __uint_as_float((u32)(k0 >> 24));
            float Dx = ncx - S.x, Dy = ncy - S.y, Dz = ncz - S.z;
            float D2 = Dx * Dx + Dy * Dy + Dz * Dz;
            float t0 = sqrtf(maxmd) * 1.0001f + S.w;
            float thr = t0 * t0 * 1.0002f + 1e-12f;
            active = (D2 <= thr);
        }
        u64 mask = __ballot(active);

        // C: this wave processes its own active chunks (64 lanes = 64 points each)
        while (mask) {
            int cb = __ffsll(mask) - 1;
            mask &= mask - 1;
            int c = (wv << 6) + cb;
            int pos = (c << 6) + lane;
            float4 P = pts[pos];
            float m = mdbuf[pos];
            float d = sq_dist_nofma(P.x, P.y, P.z, ncx, ncy, ncz);
            float m2 = fminf(m, d);
            mdbuf[pos] = m2;
            u64 kk = pack_key(m2, __float_as_int(P.w), c);
            u64 kr = kk;
            #pragma unroll
            for (int off = 32; off; off >>= 1) {
                u64 k2 = __shfl_xor(kr, off, 64);
                if (k2 > kr) kr = k2;
            }
            if (kk == kr) {                      // unique owner lane
                keys[c] = kr;
                wxyz[c] = make_float4(P.x, P.y, P.z, 0.f);
            }
        }
        __syncthreads();                         // barrier 2
    }
}

// K5: ball query, one wave per dst. First K in-radius src indices in ascending order.
__global__ void ball_kernel(const float* __restrict__ sx, const float* __restrict__ sy,
                            const float* __restrict__ sz, const float* __restrict__ sn,
                            const int* __restrict__ idx,
                            const float* __restrict__ coord, const int* __restrict__ batch,
                            int N, int n_dst,
                            float* __restrict__ out_coord, float* __restrict__ out_esrc,
                            float* __restrict__ out_edst, float* __restrict__ out_deg,
                            float* __restrict__ out_batch,
                            int* __restrict__ nbr_i, int* __restrict__ deg_i) {
    const int d    = blockIdx.x;
    const int lane = threadIdx.x;   // block of 64
    __shared__ int nbr[KNBR];

    const int id = idx[d];
    const float cx = sx[id], cy = sy[id], cz = sz[id];
    const float dn = sn[id];
    const float RR = (float)(0.08 * 0.08);

    int cnt = 0;
    for (int base = 0; base < N && cnt < KNBR; base += 64) {
        int i = base + lane;
        bool in = false;
        if (i < N) {
            float t     = __fmul_rn(sx[i], cx);
            float inner = __fmaf_rn(sy[i], cy, t);
            inner       = __fmaf_rn(sz[i], cz, inner);
            float d2    = __fsub_rn(__fadd_rn(dn, sn[i]), __fmul_rn(2.0f, inner));
            in = (d2 <= RR);
        }
        unsigned long long m = __ballot(in);
        int pos = cnt + __popcll(m & ((1ull << lane) - 1ull));
        if (in && pos < KNBR) nbr[pos] = i;
        cnt += (int)__popcll(m);
    }
    __syncthreads();

    int deg = cnt < KNBR ? cnt : KNBR;
    if (lane < KNBR) {
        int e = (lane < deg) ? nbr[lane] : -1;
        out_esrc[d * KNBR + lane] = (float)e;
        out_edst[d * KNBR + lane] = (float)((lane < deg) ? d : -1);
        nbr_i[d * KNBR + lane] = e;
    }
    if (lane == 0) { out_deg[d] = (float)deg; deg_i[d] = deg; }
    if (lane < 3)  out_coord[d * 3 + lane] = coord[id * 3 + lane];
    if (lane == 3) out_batch[d] = (float)batch[id];
}

// K6: scatter-mean of gathered features. One block per dst, one thread per feature dim.
__global__ void agg_kernel(const float* __restrict__ feat,
                           const int* __restrict__ nbr_i, const int* __restrict__ deg_i,
                           int F, float* __restrict__ out_feat) {
    const int d = blockIdx.x;
    const int t = threadIdx.x;  // F threads
    const int deg = deg_i[d];
    float acc = 0.0f;
    for (int k = 0; k < deg; ++k) {
        int nb = nbr_i[d * KNBR + k];
        acc = __fadd_rn(acc, feat[nb * F + t]);
    }
    float den = (float)(deg > 0 ? deg : 1);
    out_feat[d * F + t] = acc / den;
}

extern "C" void kernel_launch(void* const* d_in, const int* in_sizes, int n_in,
                              void* d_out, int out_size, void* d_ws, size_t ws_size,
                              hipStream_t stream) {
    const float* coord = (const float*)d_in[0];
    const float* feat  = (const float*)d_in[1];
    const int*   batch = (const int*)d_in[2];

    const int N      = in_sizes[0] / 3;
    const int F      = in_sizes[1] / N;
    const int n_dst  = N / 4;                 // RATIO = 0.25
    const int nchunk = (N + 63) / 64;         // 313

    // workspace layout (pts 16B-aligned: 4N floats precede it; N=20000 -> 320000 B)
    float*  sx      = (float*)d_ws;
    float*  sy      = sx + N;
    float*  sz      = sy + N;
    float*  sn      = sz + N;
    float4* pts     = (float4*)(sn + N);      // FCAP packed points
    float4* spheres = pts + FCAP;             // MAXCHUNK
    float4* wxyz_g  = spheres + MAXCHUNK;     // MAXCHUNK winner coords
    float*  mdbuf   = (float*)(wxyz_g + MAXCHUNK);    // FCAP floats
    u64*    ckeys   = (u64*)(mdbuf + FCAP);   // MAXCHUNK (8B-aligned)
    int*    cell      = (int*)(ckeys + MAXCHUNK);
    int*    rank      = cell + N;
    int*    hist      = rank + N;
    int*    cellstart = hist + NCELL;
    int*    idx       = cellstart + NCELL;
    int*    nbr_i     = idx + n_dst;
    int*    deg_i     = nbr_i + n_dst * KNBR;

    // output layout (all float32), reference return order
    float* out     = (float*)d_out;
    float* o_coord = out;                         // n_dst*3
    float* o_feat  = o_coord + (size_t)n_dst * 3; // n_dst*F
    float* o_esrc  = o_feat  + (size_t)n_dst * F; // n_dst*K
    float* o_edst  = o_esrc  + (size_t)n_dst * KNBR;
    float* o_deg   = o_edst  + (size_t)n_dst * KNBR;
    float* o_batch = o_deg   + n_dst;

    hipMemsetAsync(hist, 0, NCELL * sizeof(int), stream);
    prep_kernel<<<(N + 255) / 256, 256, 0, stream>>>(coord, N, sx, sy, sz, sn,
                                                     cell, rank, hist);
    scan_kernel<<<1, 1024, 0, stream>>>(hist, cellstart);
    scatter_kernel<<<(N + 255) / 256, 256, 0, stream>>>(sx, sy, sz, cell, rank,
                                                        cellstart, N, pts);
    pad_kernel<<<(nchunk * 64 - N + 255) / 256, 256, 0, stream>>>(pts, N, nchunk * 64);
    init_chunk_kernel<<<nchunk, 64, 0, stream>>>(pts, coord, mdbuf, spheres, ckeys,
                                                 wxyz_g);
    fps_kernel<<<1, FT, 0, stream>>>(pts, mdbuf, spheres, ckeys, wxyz_g,
                                     nchunk, n_dst, idx);
    ball_kernel<<<n_dst, 64, 0, stream>>>(sx, sy, sz, sn, idx, coord, batch, N, n_dst,
                                          o_coord, o_esrc, o_edst, o_deg, o_batch,
                                          nbr_i, deg_i);
    agg_kernel<<<n_dst, F, 0, stream>>>(feat, nbr_i, deg_i, F, o_feat);
}

// Round 9
// 18993.831 us; speedup vs baseline: 1.8131x; 1.8131x over previous
//
#include <hip/hip_runtime.h>

#define KNBR 32
#define NCELL 4096        // 16^3 Morton cells
#define MAXCHUNK 320      // ceil(20000/64)=313 <= 320
#define FCAP (MAXCHUNK * 64)
#define FT 512            // fps threads: 8 waves
#define NWAVE (FT / 64)
#define NGRP 5            // 5 * 64 = 320 >= MAXCHUNK chunk groups per lane

typedef unsigned long long u64;
typedef unsigned int u32;

// Reference-matching squared distance: ((dx*dx + dy*dy) + dz*dz), no FMA contraction.
__device__ __forceinline__ float sq_dist_nofma(float px, float py, float pz,
                                               float cx, float cy, float cz) {
    float dx = __fsub_rn(px, cx);
    float dy = __fsub_rn(py, cy);
    float dz = __fsub_rn(pz, cz);
    return __fadd_rn(__fadd_rn(__fmul_rn(dx, dx), __fmul_rn(dy, dy)), __fmul_rn(dz, dz));
}

__device__ __forceinline__ unsigned spread4(unsigned v) {
    return (v & 1u) | ((v & 2u) << 2) | ((v & 4u) << 4) | ((v & 8u) << 6);
}

// key = md_bits<<24 | (0x7FFF-orig)<<9 | chunk  (orig<32768, chunk<512).
// u64 max == (max md, then min orig); chunk id rides along. Sentinels -> key 0.
__device__ __forceinline__ u64 pack_key(float md, int orig, int c) {
    return (orig != 0x7fffffff)
        ? (((u64)__float_as_uint(md) << 24) | ((u64)(0x7FFFu - (u32)orig) << 9) | (u64)c)
        : 0ull;
}

// K1: AoS -> SoA + norms + Morton cell id + within-cell rank (counting-sort pass 1)
__global__ void prep_kernel(const float* __restrict__ coord, int N,
                            float* __restrict__ sx, float* __restrict__ sy,
                            float* __restrict__ sz, float* __restrict__ sn,
                            int* __restrict__ cell, int* __restrict__ rank,
                            int* __restrict__ hist) {
    int i = blockIdx.x * blockDim.x + threadIdx.x;
    if (i < N) {
        float x = coord[3 * i + 0];
        float y = coord[3 * i + 1];
        float z = coord[3 * i + 2];
        sx[i] = x; sy[i] = y; sz[i] = z;
        sn[i] = __fadd_rn(__fadd_rn(__fmul_rn(x, x), __fmul_rn(y, y)), __fmul_rn(z, z));
        int ix = (int)(x * 16.0f); ix = ix < 0 ? 0 : (ix > 15 ? 15 : ix);
        int iy = (int)(y * 16.0f); iy = iy < 0 ? 0 : (iy > 15 ? 15 : iy);
        int iz = (int)(z * 16.0f); iz = iz < 0 ? 0 : (iz > 15 ? 15 : iz);
        unsigned mc = spread4(ix) | (spread4(iy) << 1) | (spread4(iz) << 2);
        cell[i] = (int)mc;
        rank[i] = atomicAdd(&hist[mc], 1);
    }
}

// K2: exclusive scan of 4096-bin histogram
__global__ __launch_bounds__(1024) void scan_kernel(const int* __restrict__ hist,
                                                    int* __restrict__ cellstart) {
    __shared__ int buf[1024];
    int t = threadIdx.x;
    int h0 = hist[4 * t], h1 = hist[4 * t + 1], h2 = hist[4 * t + 2], h3 = hist[4 * t + 3];
    int s = h0 + h1 + h2 + h3;
    buf[t] = s;
    __syncthreads();
    for (int off = 1; off < 1024; off <<= 1) {
        int v = (t >= off) ? buf[t - off] : 0;
        __syncthreads();
        buf[t] += v;
        __syncthreads();
    }
    int ex = buf[t] - s;
    cellstart[4 * t]     = ex;
    cellstart[4 * t + 1] = ex + h0;
    cellstart[4 * t + 2] = ex + h0 + h1;
    cellstart[4 * t + 3] = ex + h0 + h1 + h2;
}

// K3: scatter into Morton order, packed as (x, y, z, orig_idx_bits)
__global__ void scatter_kernel(const float* __restrict__ sx, const float* __restrict__ sy,
                               const float* __restrict__ sz,
                               const int* __restrict__ cell, const int* __restrict__ rank,
                               const int* __restrict__ cellstart, int N,
                               float4* __restrict__ pts) {
    int i = blockIdx.x * blockDim.x + threadIdx.x;
    if (i < N) {
        int pos = cellstart[cell[i]] + rank[i];
        pts[pos] = make_float4(sx[i], sy[i], sz[i], __int_as_float(i));
    }
}

// K3b: sentinel padding
__global__ void pad_kernel(float4* __restrict__ pts, int N, int cap) {
    int i = N + blockIdx.x * blockDim.x + threadIdx.x;
    if (i < cap) pts[i] = make_float4(1e18f, 1e18f, 1e18f, __int_as_float(0x7fffffff));
}

// K3c: per-chunk init — md vs original point 0, chunk sphere, chunk key, winner coords.
__global__ void init_chunk_kernel(const float4* __restrict__ pts,
                                  const float* __restrict__ coord,
                                  float* __restrict__ mdbuf,
                                  float4* __restrict__ spheres,
                                  u64* __restrict__ ckeys,
                                  float4* __restrict__ wxyz_g) {
    int c = blockIdx.x, lane = threadIdx.x;
    int pos = (c << 6) + lane;
    float4 P = pts[pos];
    int orig = __float_as_int(P.w);
    bool real = (orig != 0x7fffffff);
    float c0x = coord[0], c0y = coord[1], c0z = coord[2];
    float d = sq_dist_nofma(P.x, P.y, P.z, c0x, c0y, c0z);
    float m = real ? d : -3e38f;
    mdbuf[pos] = m;
    u64 kself = pack_key(m, orig, c);
    u64 key = kself;
    float mnx = real ? P.x : 1e30f, mxx = real ? P.x : -1e30f;
    float mny = real ? P.y : 1e30f, mxy = real ? P.y : -1e30f;
    float mnz = real ? P.z : 1e30f, mxz = real ? P.z : -1e30f;
    #pragma unroll
    for (int off = 32; off; off >>= 1) {
        u64 k2 = __shfl_xor(key, off, 64);
        if (k2 > key) key = k2;
        mnx = fminf(mnx, __shfl_xor(mnx, off, 64));
        mxx = fmaxf(mxx, __shfl_xor(mxx, off, 64));
        mny = fminf(mny, __shfl_xor(mny, off, 64));
        mxy = fmaxf(mxy, __shfl_xor(mxy, off, 64));
        mnz = fminf(mnz, __shfl_xor(mnz, off, 64));
        mxz = fmaxf(mxz, __shfl_xor(mxz, off, 64));
    }
    if (kself == key) wxyz_g[c] = make_float4(P.x, P.y, P.z, 0.f);  // unique owner lane
    if (lane == 0) {
        float cx = 0.5f * (mnx + mxx), cy = 0.5f * (mny + mxy), cz = 0.5f * (mnz + mxz);
        float ex = (mxx - mnx) * 0.5f, ey = (mxy - mny) * 0.5f, ez = (mxz - mnz) * 0.5f;
        float r = sqrtf(ex * ex + ey * ey + ez * ez) * 1.0001f + 1e-7f;
        spheres[c] = make_float4(cx, cy, cz, r);
        ckeys[c] = key;
    }
}

// K4: chunked FPS, round-9 skeleton. 2 barriers/step, zero atomics, load-balanced.
// Every wave redundantly computes the full 313-chunk prune as 5 ballots
// (lane l checks chunks 64g+l) -> identical masks in every wave, no LDS handoff.
// Active chunks assigned by global rank % NWAVE -> balanced, uniform control flow.
// Race rules: kq reads pre-barrier1 (keys written only post-barrier1, read next
// step post-barrier2); wxyz snapshot pre-barrier1; sph static.
__global__ __launch_bounds__(FT)
void fps_kernel(const float4* __restrict__ pts, float* __restrict__ mdbuf,
                const float4* __restrict__ spheres_g, const u64* __restrict__ ckeys_g,
                const float4* __restrict__ wxyz_g,
                int nchunk, int n_dst, int* __restrict__ out_idx) {
    __shared__ u64    keys[MAXCHUNK];
    __shared__ float4 wxyz[MAXCHUNK];
    __shared__ float4 sph[MAXCHUNK];
    __shared__ u64    wwin[NWAVE];
    __shared__ float4 wcoord[NWAVE];

    const int tid = threadIdx.x, lane = tid & 63, wv = tid >> 6;

    for (int i = tid; i < MAXCHUNK; i += FT) {
        bool v = (i < nchunk);
        keys[i] = v ? ckeys_g[i] : 0ull;
        wxyz[i] = v ? wxyz_g[i] : make_float4(0.f, 0.f, 0.f, 0.f);
        sph[i]  = v ? spheres_g[i] : make_float4(1e18f, 1e18f, 1e18f, 0.f);
    }
    if (tid < NWAVE) wwin[tid] = 0ull;
    if (tid == 0) out_idx[0] = 0;
    __syncthreads();

    for (int s = 1; s < n_dst; ++s) {
        // --- pre-barrier reads: chunk keys for this lane's 5 chunk groups ---
        u64 kq0 = keys[lane];
        u64 kq1 = keys[64 + lane];
        u64 kq2 = keys[128 + lane];
        u64 kq3 = keys[192 + lane];
        u64 kq4 = keys[256 + lane];   // MAXCHUNK=320 entries exist; >=nchunk are 0

        // A: block argmax. This thread's phase-A key = its wave's group (waves 5-7: 0).
        u64 k0 = 0ull;
        if (wv == 0) k0 = kq0; else if (wv == 1) k0 = kq1; else if (wv == 2) k0 = kq2;
        else if (wv == 3) k0 = kq3; else if (wv == 4) k0 = kq4;
        u64 k = k0;
        #pragma unroll
        for (int off = 32; off; off >>= 1) {
            u64 k2 = __shfl_xor(k, off, 64);
            if (k2 > k) k = k2;
        }
        if (k0 == k && k0 != 0ull) {        // unique owner (keys embed chunk id)
            wwin[wv]   = k;
            wcoord[wv] = wxyz[tid];         // snapshot winner coords pre-barrier
        }
        __syncthreads();                    // barrier 1
        u64 kb = wwin[0]; int wb = 0;
        #pragma unroll
        for (int w = 1; w < NWAVE; ++w) { u64 t2 = wwin[w]; if (t2 > kb) { kb = t2; wb = w; } }
        float4 C4 = wcoord[wb];
        float ncx = C4.x, ncy = C4.y, ncz = C4.z;
        if (tid == 0) out_idx[s] = (int)(0x7FFFu - (u32)((kb >> 9) & 0x7FFFull));

        // B: full prune, redundantly per wave. Chunk 64g+lane checked by lane.
        // Pruned: for all p, d(p,nc) >= D - r > sqrt(maxmd) => no md change.
        u64 m0, m1, m2, m3, m4;
        {
            #define PRUNE(G, KQ, MOUT)                                                   \
            {                                                                            \
                int c = (G) * 64 + lane;                                                 \
                bool act = false;                                                        \
                if ((KQ) != 0ull) {                                                      \
                    float4 S = sph[c];                                                   \
                    float maxmd = __uint_as_float((u32)((KQ) >> 24));                    \
                    float Dx = ncx - S.x, Dy = ncy - S.y, Dz = ncz - S.z;                \
                    float D2 = Dx * Dx + Dy * Dy + Dz * Dz;                              \
                    float t0 = sqrtf(maxmd) * 1.0001f + S.w;                             \
                    float thr = t0 * t0 * 1.0002f + 1e-12f;                              \
                    act = (D2 <= thr);                                                   \
                }                                                                        \
                MOUT = __ballot(act);                                                    \
            }
            PRUNE(0, kq0, m0); PRUNE(1, kq1, m1); PRUNE(2, kq2, m2);
            PRUNE(3, kq3, m3); PRUNE(4, kq4, m4);
            #undef PRUNE
        }

        // C: enumerate active chunks in global order; rank % NWAVE == wv -> mine.
        // Masks are identical across waves -> consistent assignment, uniform flow.
        int rank = 0;
        #pragma unroll
        for (int g = 0; g < NGRP; ++g) {
            u64 m = (g == 0) ? m0 : (g == 1) ? m1 : (g == 2) ? m2 : (g == 3) ? m3 : m4;
            while (m) {
                int b = __ffsll((unsigned long long)m) - 1;
                m &= m - 1;
                if ((rank & (NWAVE - 1)) == wv) {
                    int c = (g << 6) + b;
                    int pos = (c << 6) + lane;
                    float4 P = pts[pos];
                    float md = mdbuf[pos];
                    float d = sq_dist_nofma(P.x, P.y, P.z, ncx, ncy, ncz);
                    float md2 = fminf(md, d);
                    mdbuf[pos] = md2;
                    u64 kk = pack_key(md2, __float_as_int(P.w), c);
                    u64 kr = kk;
                    #pragma unroll
                    for (int off = 32; off; off >>= 1) {
                        u64 k2 = __shfl_xor(kr, off, 64);
                        if (k2 > kr) kr = k2;
                    }
                    if (kk == kr) {          // unique owner lane
                        keys[c] = kr;
                        wxyz[c] = make_float4(P.x, P.y, P.z, 0.f);
                    }
                }
                ++rank;
            }
        }
        __syncthreads();                    // barrier 2
    }
}

// K5: ball query, one wave per dst. First K in-radius src indices in ascending order.
__global__ void ball_kernel(const float* __restrict__ sx, const float* __restrict__ sy,
                            const float* __restrict__ sz, const float* __restrict__ sn,
                            const int* __restrict__ idx,
                            const float* __restrict__ coord, const int* __restrict__ batch,
                            int N, int n_dst,
                            float* __restrict__ out_coord, float* __restrict__ out_esrc,
                            float* __restrict__ out_edst, float* __restrict__ out_deg,
                            float* __restrict__ out_batch,
                            int* __restrict__ nbr_i, int* __restrict__ deg_i) {
    const int d    = blockIdx.x;
    const int lane = threadIdx.x;   // block of 64
    __shared__ int nbr[KNBR];

    const int id = idx[d];
    const float cx = sx[id], cy = sy[id], cz = sz[id];
    const float dn = sn[id];
    const float RR = (float)(0.08 * 0.08);

    int cnt = 0;
    for (int base = 0; base < N && cnt < KNBR; base += 64) {
        int i = base + lane;
        bool in = false;
        if (i < N) {
            float t     = __fmul_rn(sx[i], cx);
            float inner = __fmaf_rn(sy[i], cy, t);
            inner       = __fmaf_rn(sz[i], cz, inner);
            float d2    = __fsub_rn(__fadd_rn(dn, sn[i]), __fmul_rn(2.0f, inner));
            in = (d2 <= RR);
        }
        unsigned long long m = __ballot(in);
        int pos = cnt + __popcll(m & ((1ull << lane) - 1ull));
        if (in && pos < KNBR) nbr[pos] = i;
        cnt += (int)__popcll(m);
    }
    __syncthreads();

    int deg = cnt < KNBR ? cnt : KNBR;
    if (lane < KNBR) {
        int e = (lane < deg) ? nbr[lane] : -1;
        out_esrc[d * KNBR + lane] = (float)e;
        out_edst[d * KNBR + lane] = (float)((lane < deg) ? d : -1);
        nbr_i[d * KNBR + lane] = e;
    }
    if (lane == 0) { out_deg[d] = (float)deg; deg_i[d] = deg; }
    if (lane < 3)  out_coord[d * 3 + lane] = coord[id * 3 + lane];
    if (lane == 3) out_batch[d] = (float)batch[id];
}

// K6: scatter-mean of gathered features. One block per dst, one thread per feature dim.
__global__ void agg_kernel(const float* __restrict__ feat,
                           const int* __restrict__ nbr_i, const int* __restrict__ deg_i,
                           int F, float* __restrict__ out_feat) {
    const int d = blockIdx.x;
    const int t = threadIdx.x;  // F threads
    const int deg = deg_i[d];
    float acc = 0.0f;
    for (int k = 0; k < deg; ++k) {
        int nb = nbr_i[d * KNBR + k];
        acc = __fadd_rn(acc, feat[nb * F + t]);
    }
    float den = (float)(deg > 0 ? deg : 1);
    out_feat[d * F + t] = acc / den;
}

extern "C" void kernel_launch(void* const* d_in, const int* in_sizes, int n_in,
                              void* d_out, int out_size, void* d_ws, size_t ws_size,
                              hipStream_t stream) {
    const float* coord = (const float*)d_in[0];
    const float* feat  = (const float*)d_in[1];
    const int*   batch = (const int*)d_in[2];

    const int N      = in_sizes[0] / 3;
    const int F      = in_sizes[1] / N;
    const int n_dst  = N / 4;                 // RATIO = 0.25
    const int nchunk = (N + 63) / 64;         // 313

    // workspace layout (pts 16B-aligned: 4N floats precede it; N=20000 -> 320000 B)
    float*  sx      = (float*)d_ws;
    float*  sy      = sx + N;
    float*  sz      = sy + N;
    float*  sn      = sz + N;
    float4* pts     = (float4*)(sn + N);      // FCAP packed points
    float4* spheres = pts + FCAP;             // MAXCHUNK
    float4* wxyz_g  = spheres + MAXCHUNK;     // MAXCHUNK winner coords
    float*  mdbuf   = (float*)(wxyz_g + MAXCHUNK);    // FCAP floats
    u64*    ckeys   = (u64*)(mdbuf + FCAP);   // MAXCHUNK (8B-aligned)
    int*    cell      = (int*)(ckeys + MAXCHUNK);
    int*    rank      = cell + N;
    int*    hist      = rank + N;
    int*    cellstart = hist + NCELL;
    int*    idx       = cellstart + NCELL;
    int*    nbr_i     = idx + n_dst;
    int*    deg_i     = nbr_i + n_dst * KNBR;

    // output layout (all float32), reference return order
    float* out     = (float*)d_out;
    float* o_coord = out;                         // n_dst*3
    float* o_feat  = o_coord + (size_t)n_dst * 3; // n_dst*F
    float* o_esrc  = o_feat  + (size_t)n_dst * F; // n_dst*K
    float* o_edst  = o_esrc  + (size_t)n_dst * KNBR;
    float* o_deg   = o_edst  + (size_t)n_dst * KNBR;
    float* o_batch = o_deg   + n_dst;

    hipMemsetAsync(hist, 0, NCELL * sizeof(int), stream);
    prep_kernel<<<(N + 255) / 256, 256, 0, stream>>>(coord, N, sx, sy, sz, sn,
                                                     cell, rank, hist);
    scan_kernel<<<1, 1024, 0, stream>>>(hist, cellstart);
    scatter_kernel<<<(N + 255) / 256, 256, 0, stream>>>(sx, sy, sz, cell, rank,
                                                        cellstart, N, pts);
    pad_kernel<<<(nchunk * 64 - N + 255) / 256, 256, 0, stream>>>(pts, N, nchunk * 64);
    init_chunk_kernel<<<nchunk, 64, 0, stream>>>(pts, coord, mdbuf, spheres, ckeys,
                                                 wxyz_g);
    fps_kernel<<<1, FT, 0, stream>>>(pts, mdbuf, spheres, ckeys, wxyz_g,
                                     nchunk, n_dst, idx);
    ball_kernel<<<n_dst, 64, 0, stream>>>(sx, sy, sz, sn, idx, coord, batch, N, n_dst,
                                          o_coord, o_esrc, o_edst, o_deg, o_batch,
                                          nbr_i, deg_i);
    agg_kernel<<<n_dst, F, 0, stream>>>(feat, nbr_i, deg_i, F, o_feat);
}

// Round 10
// 14366.705 us; speedup vs baseline: 2.3970x; 1.3221x over previous
//
#include <hip/hip_runtime.h>

#define KNBR 32
#define NCELL 4096        // 16^3 Morton cells
#define MAXCHUNK 320      // ceil(20000/64)=313 <= 320
#define FCAP (MAXCHUNK * 64)
#define FT 512            // fps threads: 8 waves
#define NWAVE (FT / 64)

typedef unsigned long long u64;
typedef unsigned int u32;

// Reference-matching squared distance: ((dx*dx + dy*dy) + dz*dz), no FMA contraction.
__device__ __forceinline__ float sq_dist_nofma(float px, float py, float pz,
                                               float cx, float cy, float cz) {
    float dx = __fsub_rn(px, cx);
    float dy = __fsub_rn(py, cy);
    float dz = __fsub_rn(pz, cz);
    return __fadd_rn(__fadd_rn(__fmul_rn(dx, dx), __fmul_rn(dy, dy)), __fmul_rn(dz, dz));
}

__device__ __forceinline__ unsigned spread4(unsigned v) {
    return (v & 1u) | ((v & 2u) << 2) | ((v & 4u) << 4) | ((v & 8u) << 6);
}

// key = md_bits<<24 | (0x7FFF-orig)<<9 | chunk  (orig<32768, chunk<512).
// u64 max == (max md, then min orig); chunk id rides along. Sentinels -> key 0.
__device__ __forceinline__ u64 pack_key(float md, int orig, int c) {
    return (orig != 0x7fffffff)
        ? (((u64)__float_as_uint(md) << 24) | ((u64)(0x7FFFu - (u32)orig) << 9) | (u64)c)
        : 0ull;
}

// K1: AoS -> SoA + norms + Morton cell id + within-cell rank (counting-sort pass 1)
__global__ void prep_kernel(const float* __restrict__ coord, int N,
                            float* __restrict__ sx, float* __restrict__ sy,
                            float* __restrict__ sz, float* __restrict__ sn,
                            int* __restrict__ cell, int* __restrict__ rank,
                            int* __restrict__ hist) {
    int i = blockIdx.x * blockDim.x + threadIdx.x;
    if (i < N) {
        float x = coord[3 * i + 0];
        float y = coord[3 * i + 1];
        float z = coord[3 * i + 2];
        sx[i] = x; sy[i] = y; sz[i] = z;
        sn[i] = __fadd_rn(__fadd_rn(__fmul_rn(x, x), __fmul_rn(y, y)), __fmul_rn(z, z));
        int ix = (int)(x * 16.0f); ix = ix < 0 ? 0 : (ix > 15 ? 15 : ix);
        int iy = (int)(y * 16.0f); iy = iy < 0 ? 0 : (iy > 15 ? 15 : iy);
        int iz = (int)(z * 16.0f); iz = iz < 0 ? 0 : (iz > 15 ? 15 : iz);
        unsigned mc = spread4(ix) | (spread4(iy) << 1) | (spread4(iz) << 2);
        cell[i] = (int)mc;
        rank[i] = atomicAdd(&hist[mc], 1);
    }
}

// K2: exclusive scan of 4096-bin histogram
__global__ __launch_bounds__(1024) void scan_kernel(const int* __restrict__ hist,
                                                    int* __restrict__ cellstart) {
    __shared__ int buf[1024];
    int t = threadIdx.x;
    int h0 = hist[4 * t], h1 = hist[4 * t + 1], h2 = hist[4 * t + 2], h3 = hist[4 * t + 3];
    int s = h0 + h1 + h2 + h3;
    buf[t] = s;
    __syncthreads();
    for (int off = 1; off < 1024; off <<= 1) {
        int v = (t >= off) ? buf[t - off] : 0;
        __syncthreads();
        buf[t] += v;
        __syncthreads();
    }
    int ex = buf[t] - s;
    cellstart[4 * t]     = ex;
    cellstart[4 * t + 1] = ex + h0;
    cellstart[4 * t + 2] = ex + h0 + h1;
    cellstart[4 * t + 3] = ex + h0 + h1 + h2;
}

// K3: scatter into Morton order, packed as (x, y, z, orig_idx_bits)
__global__ void scatter_kernel(const float* __restrict__ sx, const float* __restrict__ sy,
                               const float* __restrict__ sz,
                               const int* __restrict__ cell, const int* __restrict__ rank,
                               const int* __restrict__ cellstart, int N,
                               float4* __restrict__ pts) {
    int i = blockIdx.x * blockDim.x + threadIdx.x;
    if (i < N) {
        int pos = cellstart[cell[i]] + rank[i];
        pts[pos] = make_float4(sx[i], sy[i], sz[i], __int_as_float(i));
    }
}

// K3b: sentinel padding
__global__ void pad_kernel(float4* __restrict__ pts, int N, int cap) {
    int i = N + blockIdx.x * blockDim.x + threadIdx.x;
    if (i < cap) pts[i] = make_float4(1e18f, 1e18f, 1e18f, __int_as_float(0x7fffffff));
}

// K3c: per-chunk init — md vs original point 0, chunk sphere, chunk key, winner coords.
__global__ void init_chunk_kernel(const float4* __restrict__ pts,
                                  const float* __restrict__ coord,
                                  float* __restrict__ mdbuf,
                                  float4* __restrict__ spheres,
                                  u64* __restrict__ ckeys,
                                  float4* __restrict__ wxyz_g) {
    int c = blockIdx.x, lane = threadIdx.x;
    int pos = (c << 6) + lane;
    float4 P = pts[pos];
    int orig = __float_as_int(P.w);
    bool real = (orig != 0x7fffffff);
    float c0x = coord[0], c0y = coord[1], c0z = coord[2];
    float d = sq_dist_nofma(P.x, P.y, P.z, c0x, c0y, c0z);
    float m = real ? d : -3e38f;
    mdbuf[pos] = m;
    u64 kself = pack_key(m, orig, c);
    u64 key = kself;
    float mnx = real ? P.x : 1e30f, mxx = real ? P.x : -1e30f;
    float mny = real ? P.y : 1e30f, mxy = real ? P.y : -1e30f;
    float mnz = real ? P.z : 1e30f, mxz = real ? P.z : -1e30f;
    #pragma unroll
    for (int off = 32; off; off >>= 1) {
        u64 k2 = __shfl_xor(key, off, 64);
        if (k2 > key) key = k2;
        mnx = fminf(mnx, __shfl_xor(mnx, off, 64));
        mxx = fmaxf(mxx, __shfl_xor(mxx, off, 64));
        mny = fminf(mny, __shfl_xor(mny, off, 64));
        mxy = fmaxf(mxy, __shfl_xor(mxy, off, 64));
        mnz = fminf(mnz, __shfl_xor(mnz, off, 64));
        mxz = fmaxf(mxz, __shfl_xor(mxz, off, 64));
    }
    if (kself == key) wxyz_g[c] = make_float4(P.x, P.y, P.z, 0.f);  // unique owner lane
    if (lane == 0) {
        float cx = 0.5f * (mnx + mxx), cy = 0.5f * (mny + mxy), cz = 0.5f * (mnz + mxz);
        float ex = (mxx - mnx) * 0.5f, ey = (mxy - mny) * 0.5f, ez = (mxz - mnz) * 0.5f;
        float r = sqrtf(ex * ex + ey * ey + ez * ez) * 1.0001f + 1e-7f;
        spheres[c] = make_float4(cx, cy, cz, r);
        ckeys[c] = key;
    }
}

// K4: chunked FPS, round-10 skeleton: permuted chunk ownership.
// Thread wv*64+lane owns chunk c = lane*8+wv, so Morton-consecutive chunks
// (which cluster around the new center) spread across all 8 waves.
// Each wave processes exactly the chunks it pruned itself: no queue, no atomics,
// no rank counting, 2 barriers/step. Sphere held in registers (static map).
// Race rules: keys/wxyz read pre-barrier1 (phase C writes them only post-barrier1;
// next read is post-barrier2).
__global__ __launch_bounds__(FT)
void fps_kernel(const float4* __restrict__ pts, float* __restrict__ mdbuf,
                const float4* __restrict__ spheres_g, const u64* __restrict__ ckeys_g,
                const float4* __restrict__ wxyz_g,
                int nchunk, int n_dst, int* __restrict__ out_idx) {
    __shared__ u64    keys[MAXCHUNK];
    __shared__ float4 wxyz[MAXCHUNK];
    __shared__ u64    wwin[NWAVE];
    __shared__ float4 wcoord[NWAVE];

    const int tid = threadIdx.x, lane = tid & 63, wv = tid >> 6;
    const int myc = (lane << 3) + wv;      // permuted ownership: chunk -> wave = c & 7

    for (int i = tid; i < MAXCHUNK; i += FT) {
        bool v = (i < nchunk);
        keys[i] = v ? ckeys_g[i] : 0ull;
        wxyz[i] = v ? wxyz_g[i] : make_float4(0.f, 0.f, 0.f, 0.f);
    }
    float4 S = make_float4(1e18f, 1e18f, 1e18f, 0.f);
    if (myc < nchunk) S = spheres_g[myc];  // static map: sphere lives in 4 VGPRs
    if (tid < NWAVE) wwin[tid] = 0ull;
    if (tid == 0) out_idx[0] = 0;
    __syncthreads();

    for (int s = 1; s < n_dst; ++s) {
        // pre-barrier reads: own chunk's key (also the argmax input)
        u64 k0 = (myc < nchunk) ? keys[myc] : 0ull;
        u64 k = k0;
        #pragma unroll
        for (int off = 32; off; off >>= 1) {
            u64 k2 = __shfl_xor(k, off, 64);
            if (k2 > k) k = k2;
        }
        if (k0 == k && k0 != 0ull) {       // unique owner (keys embed chunk id)
            wwin[wv]   = k;
            wcoord[wv] = wxyz[myc];        // snapshot winner coords pre-barrier
        }
        __syncthreads();                   // barrier 1
        u64 kb = wwin[0]; int wb = 0;
        #pragma unroll
        for (int w = 1; w < NWAVE; ++w) { u64 t2 = wwin[w]; if (t2 > kb) { kb = t2; wb = w; } }
        float4 C4 = wcoord[wb];
        float ncx = C4.x, ncy = C4.y, ncz = C4.z;
        if (tid == 0) out_idx[s] = (int)(0x7FFFu - (u32)((kb >> 9) & 0x7FFFull));

        // B: prune own chunk (registers only).
        // Pruned: for all p, d(p,nc) >= D - r > sqrt(maxmd) => no md change.
        // Winner's chunk never pruned (nc inside its own sphere).
        bool act = false;
        if (k0 != 0ull) {
            float maxmd = __uint_as_float((u32)(k0 >> 24));
            float Dx = ncx - S.x, Dy = ncy - S.y, Dz = ncz - S.z;
            float D2 = Dx * Dx + Dy * Dy + Dz * Dz;
            float t0 = sqrtf(maxmd) * 1.0001f + S.w;
            float thr = t0 * t0 * 1.0002f + 1e-12f;
            act = (D2 <= thr);
        }
        u64 m = __ballot(act);

        // C: this wave processes the chunks it pruned (bit b -> chunk (b<<3)+wv).
        while (m) {
            int b = __ffsll(m) - 1;
            m &= m - 1;
            int c = (b << 3) + wv;
            int pos = (c << 6) + lane;
            float4 P = pts[pos];
            float md = mdbuf[pos];
            float d = sq_dist_nofma(P.x, P.y, P.z, ncx, ncy, ncz);
            float md2 = fminf(md, d);
            mdbuf[pos] = md2;
            u64 kk = pack_key(md2, __float_as_int(P.w), c);
            u64 kr = kk;
            #pragma unroll
            for (int off = 32; off; off >>= 1) {
                u64 k2 = __shfl_xor(kr, off, 64);
                if (k2 > kr) kr = k2;
            }
            if (kk == kr) {                // unique owner lane
                keys[c] = kr;
                wxyz[c] = make_float4(P.x, P.y, P.z, 0.f);
            }
        }
        __syncthreads();                   // barrier 2
    }
}

// K5: ball query, one wave per dst. First K in-radius src indices in ascending order.
__global__ void ball_kernel(const float* __restrict__ sx, const float* __restrict__ sy,
                            const float* __restrict__ sz, const float* __restrict__ sn,
                            const int* __restrict__ idx,
                            const float* __restrict__ coord, const int* __restrict__ batch,
                            int N, int n_dst,
                            float* __restrict__ out_coord, float* __restrict__ out_esrc,
                            float* __restrict__ out_edst, float* __restrict__ out_deg,
                            float* __restrict__ out_batch,
                            int* __restrict__ nbr_i, int* __restrict__ deg_i) {
    const int d    = blockIdx.x;
    const int lane = threadIdx.x;   // block of 64
    __shared__ int nbr[KNBR];

    const int id = idx[d];
    const float cx = sx[id], cy = sy[id], cz = sz[id];
    const float dn = sn[id];
    const float RR = (float)(0.08 * 0.08);

    int cnt = 0;
    for (int base = 0; base < N && cnt < KNBR; base += 64) {
        int i = base + lane;
        bool in = false;
        if (i < N) {
            float t     = __fmul_rn(sx[i], cx);
            float inner = __fmaf_rn(sy[i], cy, t);
            inner       = __fmaf_rn(sz[i], cz, inner);
            float d2    = __fsub_rn(__fadd_rn(dn, sn[i]), __fmul_rn(2.0f, inner));
            in = (d2 <= RR);
        }
        unsigned long long m = __ballot(in);
        int pos = cnt + __popcll(m & ((1ull << lane) - 1ull));
        if (in && pos < KNBR) nbr[pos] = i;
        cnt += (int)__popcll(m);
    }
    __syncthreads();

    int deg = cnt < KNBR ? cnt : KNBR;
    if (lane < KNBR) {
        int e = (lane < deg) ? nbr[lane] : -1;
        out_esrc[d * KNBR + lane] = (float)e;
        out_edst[d * KNBR + lane] = (float)((lane < deg) ? d : -1);
        nbr_i[d * KNBR + lane] = e;
    }
    if (lane == 0) { out_deg[d] = (float)deg; deg_i[d] = deg; }
    if (lane < 3)  out_coord[d * 3 + lane] = coord[id * 3 + lane];
    if (lane == 3) out_batch[d] = (float)batch[id];
}

// K6: scatter-mean of gathered features. One block per dst, one thread per feature dim.
__global__ void agg_kernel(const float* __restrict__ feat,
                           const int* __restrict__ nbr_i, const int* __restrict__ deg_i,
                           int F, float* __restrict__ out_feat) {
    const int d = blockIdx.x;
    const int t = threadIdx.x;  // F threads
    const int deg = deg_i[d];
    float acc = 0.0f;
    for (int k = 0; k < deg; ++k) {
        int nb = nbr_i[d * KNBR + k];
        acc = __fadd_rn(acc, feat[nb * F + t]);
    }
    float den = (float)(deg > 0 ? deg : 1);
    out_feat[d * F + t] = acc / den;
}

extern "C" void kernel_launch(void* const* d_in, const int* in_sizes, int n_in,
                              void* d_out, int out_size, void* d_ws, size_t ws_size,
                              hipStream_t stream) {
    const float* coord = (const float*)d_in[0];
    const float* feat  = (const float*)d_in[1];
    const int*   batch = (const int*)d_in[2];

    const int N      = in_sizes[0] / 3;
    const int F      = in_sizes[1] / N;
    const int n_dst  = N / 4;                 // RATIO = 0.25
    const int nchunk = (N + 63) / 64;         // 313

    // workspace layout (pts 16B-aligned: 4N floats precede it; N=20000 -> 320000 B)
    float*  sx      = (float*)d_ws;
    float*  sy      = sx + N;
    float*  sz      = sy + N;
    float*  sn      = sz + N;
    float4* pts     = (float4*)(sn + N);      // FCAP packed points
    float4* spheres = pts + FCAP;             // MAXCHUNK
    float4* wxyz_g  = spheres + MAXCHUNK;     // MAXCHUNK winner coords
    float*  mdbuf   = (float*)(wxyz_g + MAXCHUNK);    // FCAP floats
    u64*    ckeys   = (u64*)(mdbuf + FCAP);   // MAXCHUNK (8B-aligned)
    int*    cell      = (int*)(ckeys + MAXCHUNK);
    int*    rank      = cell + N;
    int*    hist      = rank + N;
    int*    cellstart = hist + NCELL;
    int*    idx       = cellstart + NCELL;
    int*    nbr_i     = idx + n_dst;
    int*    deg_i     = nbr_i + n_dst * KNBR;

    // output layout (all float32), reference return order
    float* out     = (float*)d_out;
    float* o_coord = out;                         // n_dst*3
    float* o_feat  = o_coord + (size_t)n_dst * 3; // n_dst*F
    float* o_esrc  = o_feat  + (size_t)n_dst * F; // n_dst*K
    float* o_edst  = o_esrc  + (size_t)n_dst * KNBR;
    float* o_deg   = o_edst  + (size_t)n_dst * KNBR;
    float* o_batch = o_deg   + n_dst;

    hipMemsetAsync(hist, 0, NCELL * sizeof(int), stream);
    prep_kernel<<<(N + 255) / 256, 256, 0, stream>>>(coord, N, sx, sy, sz, sn,
                                                     cell, rank, hist);
    scan_kernel<<<1, 1024, 0, stream>>>(hist, cellstart);
    scatter_kernel<<<(N + 255) / 256, 256, 0, stream>>>(sx, sy, sz, cell, rank,
                                                        cellstart, N, pts);
    pad_kernel<<<(nchunk * 64 - N + 255) / 256, 256, 0, stream>>>(pts, N, nchunk * 64);
    init_chunk_kernel<<<nchunk, 64, 0, stream>>>(pts, coord, mdbuf, spheres, ckeys,
                                                 wxyz_g);
    fps_kernel<<<1, FT, 0, stream>>>(pts, mdbuf, spheres, ckeys, wxyz_g,
                                     nchunk, n_dst, idx);
    ball_kernel<<<n_dst, 64, 0, stream>>>(sx, sy, sz, sn, idx, coord, batch, N, n_dst,
                                          o_coord, o_esrc, o_edst, o_deg, o_batch,
                                          nbr_i, deg_i);
    agg_kernel<<<n_dst, F, 0, stream>>>(feat, nbr_i, deg_i, F, o_feat);
}